// Round 1
// baseline (75.204 us; speedup 1.0000x reference)
//
#include <hip/hip_runtime.h>
#include <math.h>

#define GROUP 8
#define NG 4
#define C2 32
#define CTOT 64
#define L 4096
#define BB 4
#define NSAMP 2048
#define LOG2PI_F 1.8377997f  // not used; keep exact below

__device__ __forceinline__ float clipf(float x, float lo, float hi) {
    return fminf(fmaxf(x, lo), hi);
}

// Block: 256 threads. tid>>3 = q (0..31) -> (b,pos) pair; tid&7 = k -> n-stripe (n = nn*8+k).
// Each thread owns 4 rows (ns = 0..3) of its (b,pos).
// Grid: (B*L)/32 = 512 blocks.
__global__ __launch_bounds__(256) void gqreg_kernel(
    const float* __restrict__ z, const float* __restrict__ prior,
    float* __restrict__ out /* zhat [B][C2][L] then indices-as-float [B][NG][L] */)
{
    __shared__ float4 s_lds[NSAMP * 2];   // 64 KB: sample n at entries 2n, 2n+1
    __shared__ float nlp_lds[NSAMP];      // 8 KB

    const float LOG2PI = 1.837877066409345339868941870342f;
    const int tid = threadIdx.x;

    // ---- stage prior samples into LDS (coalesced float4) ----
    const float4* p4 = (const float4*)prior;
    #pragma unroll
    for (int i = 0; i < 16; ++i) {
        s_lds[tid + i * 256] = p4[tid + i * 256];
    }
    __syncthreads();

    // ---- nlp_sum[n] = -0.5*sum(s^2) - 0.5*G*log(2pi) ----
    #pragma unroll
    for (int i = 0; i < 8; ++i) {
        int n = tid + i * 256;
        float4 u = s_lds[2 * n], v = s_lds[2 * n + 1];
        float ss = u.x * u.x + u.y * u.y + u.z * u.z + u.w * u.w
                 + v.x * v.x + v.y * v.y + v.z * v.z + v.w * v.w;
        nlp_lds[n] = -0.5f * ss - 0.5f * (float)GROUP * LOG2PI;
    }
    __syncthreads();

    // ---- per-row coefficients ----
    const int q = tid >> 3;
    const int k = tid & 7;
    const int Q = blockIdx.x * 32 + q;      // 0 .. B*L-1
    const int b = Q >> 12;                  // /4096
    const int pos = Q & (L - 1);
    const float* zb = z + (size_t)b * CTOT * L + pos;

    float ca[NG][GROUP];   // -0.5 * inv_var
    float cbv[NG][GROUP];  // mu * inv_var
    float rc[NG];
    #pragma unroll
    for (int ns = 0; ns < NG; ++ns) {
        float rcsum = 0.f, logstdsum = 0.f;
        #pragma unroll
        for (int g = 0; g < GROUP; ++g) {
            int ch = g * NG + ns;
            float mu = zb[(size_t)ch * L];
            float lv = zb[(size_t)(C2 + ch) * L];
            lv = clipf(lv, -30.f, 20.f);
            float stdv = expf(0.5f * lv);
            float iv = 1.0f / (stdv * stdv);
            ca[ns][g] = -0.5f * iv;
            cbv[ns][g] = mu * iv;
            rcsum += mu * mu * iv;
            logstdsum += logf(stdv);
        }
        rc[ns] = -0.5f * rcsum - logstdsum - 0.5f * (float)GROUP * LOG2PI;
    }

    // ---- argmax scan: stripe k handles n = nn*8 + k, nn ascending ----
    float best[NG] = {-INFINITY, -INFINITY, -INFINITY, -INFINITY};
    int bidx[NG] = {0, 0, 0, 0};

    #pragma unroll 2
    for (int nn = 0; nn < NSAMP / 8; ++nn) {
        int n = nn * 8 + k;
        float4 u = s_lds[2 * n], v = s_lds[2 * n + 1];
        float s[GROUP] = {u.x, u.y, u.z, u.w, v.x, v.y, v.z, v.w};
        float s2[GROUP];
        #pragma unroll
        for (int g = 0; g < GROUP; ++g) s2[g] = s[g] * s[g];
        float nlp = nlp_lds[n];
        #pragma unroll
        for (int ns = 0; ns < NG; ++ns) {
            float acc1 = 0.f, acc2 = 0.f;
            #pragma unroll
            for (int g = 0; g < GROUP; ++g) {
                acc1 = fmaf(ca[ns][g], s2[g], acc1);
                acc2 = fmaf(cbv[ns][g], s[g], acc2);
            }
            float f = ((acc1 + acc2) + rc[ns]) - nlp;
            if (f > best[ns]) { best[ns] = f; bidx[ns] = n; }
        }
    }

    // ---- reduce argmax across the 8 stripe lanes (first-max = lowest n on tie) ----
    #pragma unroll
    for (int ns = 0; ns < NG; ++ns) {
        #pragma unroll
        for (int m = 1; m < 8; m <<= 1) {
            float os = __shfl_xor(best[ns], m, 64);
            int oi = __shfl_xor(bidx[ns], m, 64);
            if (os > best[ns] || (os == best[ns] && oi < bidx[ns])) {
                best[ns] = os; bidx[ns] = oi;
            }
        }
    }

    // ---- write outputs (lane k==0 of each 8-lane group) ----
    if (k == 0) {
        float* zout = out + (size_t)b * C2 * L + pos;
        float* iout = out + (size_t)BB * C2 * L + (size_t)b * NG * L + pos;
        #pragma unroll
        for (int ns = 0; ns < NG; ++ns) {
            int n = bidx[ns];
            iout[(size_t)ns * L] = (float)n;
            float4 u = s_lds[2 * n], v = s_lds[2 * n + 1];
            float sv[GROUP] = {u.x, u.y, u.z, u.w, v.x, v.y, v.z, v.w};
            #pragma unroll
            for (int g = 0; g < GROUP; ++g) {
                zout[(size_t)(g * NG + ns) * L] = sv[g];
            }
        }
    }
}

extern "C" void kernel_launch(void* const* d_in, const int* in_sizes, int n_in,
                              void* d_out, int out_size, void* d_ws, size_t ws_size,
                              hipStream_t stream) {
    const float* z = (const float*)d_in[0];
    const float* prior = (const float*)d_in[1];
    float* out = (float*)d_out;
    dim3 grid((BB * L) / 32);
    dim3 block(256);
    hipLaunchKernelGGL(gqreg_kernel, grid, block, 0, stream, z, prior, out);
}

// Round 2
// 60.932 us; speedup vs baseline: 1.2342x; 1.2342x over previous
//
#include <hip/hip_runtime.h>
#include <math.h>

#define GROUP 8
#define NG 4
#define C2 32
#define CTOT 64
#define L 4096
#define BB 4
#define NSAMP 2048
#define KL 16      // lanes (n-stripes) per q
#define QPB 32     // (b,pos) pairs per block
#define THREADS 512

// Block: 512 threads. tid>>4 = q (0..31) -> (b,pos) pair; tid&15 = k -> n-stripe
// (n = nn*16+k, 128 iters). Each thread owns the 4 ns-rows of its (b,pos).
// Grid: (B*L)/32 = 512 blocks; LDS 64KB -> 2 blocks/CU -> 16 waves/CU (4/SIMD).
//
// argmax_n score[r,n]; score = sum_g[-0.5*iv*s2 + mu*iv*s] + rc[r] - nlp[n].
// rc[r] is row-constant (monotone under fp32 add) -> dropped.
// -nlp[n] = +0.5*sum_g s2[g] + const -> folded: ca = 0.5*(1-iv), cb = mu*iv,
// score' = sum_g (ca*s + cb)*s.
__global__ __launch_bounds__(THREADS) void gqreg_kernel(
    const float* __restrict__ z, const float* __restrict__ prior,
    float* __restrict__ out /* zhat [B][C2][L] then indices-as-float [B][NG][L] */)
{
    __shared__ float4 s_lo[NSAMP];   // 32 KB: sample n, g=0..3
    __shared__ float4 s_hi[NSAMP];   // 32 KB: sample n, g=4..7

    const int tid = threadIdx.x;

    // ---- stage prior samples into LDS: thread t' stages whole sample t' ----
    const float4* p4 = (const float4*)prior;
    #pragma unroll
    for (int i = 0; i < 4; ++i) {
        int n = tid + i * THREADS;
        s_lo[n] = p4[2 * n];
        s_hi[n] = p4[2 * n + 1];
    }

    // ---- per-row coefficients (no LDS dependency; overlaps staging) ----
    const int k = tid & (KL - 1);
    const int q = tid >> 4;
    const int Q = blockIdx.x * QPB + q;     // 0 .. B*L-1
    const int b = Q >> 12;                  // /4096
    const int pos = Q & (L - 1);
    const float* zb = z + (size_t)b * CTOT * L + pos;

    float ca[NG][GROUP];   // 0.5*(1 - inv_var)
    float cb[NG][GROUP];   // mu * inv_var
    #pragma unroll
    for (int ns = 0; ns < NG; ++ns) {
        #pragma unroll
        for (int g = 0; g < GROUP; ++g) {
            int ch = g * NG + ns;
            float mu = zb[(size_t)ch * L];
            float lv = zb[(size_t)(C2 + ch) * L];
            lv = fminf(fmaxf(lv, -30.f), 20.f);
            float iv = expf(-lv);
            ca[ns][g] = 0.5f - 0.5f * iv;
            cb[ns][g] = mu * iv;
        }
    }

    __syncthreads();

    // ---- argmax scan: stripe k handles n = nn*16 + k ----
    float best[NG] = {-INFINITY, -INFINITY, -INFINITY, -INFINITY};
    int bidx[NG] = {0, 0, 0, 0};

    #pragma unroll 4
    for (int nn = 0; nn < NSAMP / KL; ++nn) {
        int n = nn * KL + k;
        float4 u = s_lo[n], v = s_hi[n];
        float s[GROUP] = {u.x, u.y, u.z, u.w, v.x, v.y, v.z, v.w};
        #pragma unroll
        for (int ns = 0; ns < NG; ++ns) {
            float acc = 0.f;
            #pragma unroll
            for (int g = 0; g < GROUP; ++g) {
                float t = fmaf(ca[ns][g], s[g], cb[ns][g]);
                acc = fmaf(t, s[g], acc);
            }
            if (acc > best[ns]) { best[ns] = acc; bidx[ns] = n; }
        }
    }

    // ---- reduce argmax across the 16 stripe lanes (tie -> lowest n) ----
    #pragma unroll
    for (int ns = 0; ns < NG; ++ns) {
        #pragma unroll
        for (int m = 1; m < KL; m <<= 1) {
            float os = __shfl_xor(best[ns], m, 64);
            int oi = __shfl_xor(bidx[ns], m, 64);
            if (os > best[ns] || (os == best[ns] && oi < bidx[ns])) {
                best[ns] = os; bidx[ns] = oi;
            }
        }
    }

    // ---- write outputs (lane k==0 of each 16-lane group) ----
    if (k == 0) {
        float* zout = out + (size_t)b * C2 * L + pos;
        float* iout = out + (size_t)BB * C2 * L + (size_t)b * NG * L + pos;
        #pragma unroll
        for (int ns = 0; ns < NG; ++ns) {
            int n = bidx[ns];
            iout[(size_t)ns * L] = (float)n;
            float4 u = s_lo[n], v = s_hi[n];
            float sv[GROUP] = {u.x, u.y, u.z, u.w, v.x, v.y, v.z, v.w};
            #pragma unroll
            for (int g = 0; g < GROUP; ++g) {
                zout[(size_t)(g * NG + ns) * L] = sv[g];
            }
        }
    }
}

extern "C" void kernel_launch(void* const* d_in, const int* in_sizes, int n_in,
                              void* d_out, int out_size, void* d_ws, size_t ws_size,
                              hipStream_t stream) {
    const float* z = (const float*)d_in[0];
    const float* prior = (const float*)d_in[1];
    float* out = (float*)d_out;
    dim3 grid((BB * L) / QPB);
    dim3 block(THREADS);
    hipLaunchKernelGGL(gqreg_kernel, grid, block, 0, stream, z, prior, out);
}